// Round 8
// baseline (262.053 us; speedup 1.0000x reference)
//
#include <hip/hip_runtime.h>
#include <math.h>

// BundleAdjustmentModel: project N 3D points into V=64 camera views.
// out[v][n] = (u,v), u = -f*X/safe_z + cx, v = f*Y/safe_z + cy,
// [X,Y,Z] = R_v * p_n + t_v, R_v = Rx*Ry*Rz (euler xyz), t_v = (tx,ty,-(softplus(d)+0.25))
//
// Counter-backed ledger:
//  - dur_us = fill(155) + harness(47, measured in r3) + kernel.
//    Current kernel ~58us vs 41us write floor (256MB @ fill's 6.6 TB/s).
//  - NT stores: 2.63x write amplification -> never.
//  - Reads: keep points loaded ONCE (more re-reads monotonically hurt).
//  - Exonerated by A/B: store width (r5), aggregate write linearity (r6),
//    per-wave fence serialization / unroll (r7).
//  - Remaining axis: WAVE COUNT. More waves = slower (r5 3908w=58us,
//    r1 15632w=74us); fill hits 6.6 TB/s at ~3 waves/CU. Each resident wave
//    is one interleaved 1KB-burst stream at the controllers; fewer, fatter
//    streams = more fill-like.
// This round (single variable vs r7): PPT=4 -> 489 blocks / 1956 waves
// (~1.9/SIMD), each wave emits 2KB contiguous per row-visit (2x float4/thread).

#define NVIEW 64
#define BLOCK 256
#define Z_EPS 1e-4f

__device__ __forceinline__ float softplus_f(float x) {
    // stable: max(x,0) + log1p(exp(-|x|))
    return fmaxf(x, 0.0f) + log1pf(expf(-fabsf(x)));
}

__global__ __launch_bounds__(BLOCK) void ba_project_kernel(
    const float* __restrict__ points,          // (N,3)
    const float* __restrict__ euler,           // (V,3)
    const float* __restrict__ txy,             // (V,2)
    const float* __restrict__ tdr,             // (V,)
    const float* __restrict__ focal_raw,       // (1,)
    const int*   __restrict__ cxp,             // (1,)
    const int*   __restrict__ cyp,             // (1,)
    float2* __restrict__ out,                  // (V,N) float2
    int N)
{
    // Per-view constants: rows [-f*R0|-f*tx], [f*R1|f*ty], [R2|tz],
    // 3 float4s per view. Broadcast ds_read_b128 -> conflict-free.
    __shared__ float4 vd[NVIEW * 3];

    const int tid = threadIdx.x;
    const float focal = softplus_f(focal_raw[0]) + 50.0f;

    if (tid < NVIEW) {
        float ex = euler[tid * 3 + 0];
        float ey = euler[tid * 3 + 1];
        float ez = euler[tid * 3 + 2];
        float sx, cx_, sy, cy_, sz, cz;
        sincosf(ex, &sx, &cx_);
        sincosf(ey, &sy, &cy_);
        sincosf(ez, &sz, &cz);
        // R = Rx @ Ry @ Rz
        float r00 = cy_ * cz;
        float r01 = -cy_ * sz;
        float r02 = sy;
        float r10 = cx_ * sz + sx * sy * cz;
        float r11 = cx_ * cz - sx * sy * sz;
        float r12 = -sx * cy_;
        float r20 = sx * sz - cx_ * sy * cz;
        float r21 = sx * cz + cx_ * sy * sz;
        float r22 = cx_ * cy_;

        float tx = txy[tid * 2 + 0];
        float ty = txy[tid * 2 + 1];
        float tz = -(softplus_f(tdr[tid]) + 0.25f);

        vd[tid * 3 + 0] = make_float4(-focal * r00, -focal * r01, -focal * r02, -focal * tx);
        vd[tid * 3 + 1] = make_float4( focal * r10,  focal * r11,  focal * r12,  focal * ty);
        vd[tid * 3 + 2] = make_float4(r20, r21, r22, tz);
    }
    __syncthreads();

    const float ccx = (float)cxp[0];
    const float ccy = (float)cyp[0];

    // Each thread owns 4 consecutive points {4q .. 4q+3}; loaded ONCE,
    // reused across all 64 views.
    const int q  = blockIdx.x * BLOCK + tid;
    const int n0 = q * 4;
    if (n0 >= N) return;

    float px[4], py[4], pz[4];
    if (n0 + 4 <= N) {
        // 12 floats = 3 aligned float4 loads (byte offset n0*12 = 48q, %16==0)
        const float4* src = (const float4*)(points + (size_t)n0 * 3);
        float4 L0 = src[0], L1 = src[1], L2 = src[2];
        px[0] = L0.x; py[0] = L0.y; pz[0] = L0.z;
        px[1] = L0.w; py[1] = L1.x; pz[1] = L1.y;
        px[2] = L1.z; py[2] = L1.w; pz[2] = L2.x;
        px[3] = L2.y; py[3] = L2.z; pz[3] = L2.w;
    } else {
        for (int k = 0; k < 4; ++k) {
            int i = (n0 + k < N) ? (n0 + k) * 3 : 0;
            px[k] = points[i + 0];
            py[k] = points[i + 1];
            pz[k] = points[i + 2];
        }
    }
    const int nvalid = (n0 + 4 <= N) ? 4 : (N - n0);   // 4 on the fast path

    float2* orow = out + n0;   // + v*N added per iteration

#pragma unroll 2
    for (int v = 0; v < NVIEW; ++v) {
        float4 A = vd[v * 3 + 0];
        float4 B = vd[v * 3 + 1];
        float4 C = vd[v * 3 + 2];

        float uv[8];
#pragma unroll
        for (int k = 0; k < 4; ++k) {
            float X = fmaf(A.x, px[k], fmaf(A.y, py[k], fmaf(A.z, pz[k], A.w)));
            float Y = fmaf(B.x, px[k], fmaf(B.y, py[k], fmaf(B.z, pz[k], B.w)));
            float Z = fmaf(C.x, px[k], fmaf(C.y, py[k], fmaf(C.z, pz[k], C.w)));
            float sg = (Z >= 0.0f) ? 1.0f : -1.0f;
            float t  = __builtin_amdgcn_rcpf(sg * fmaxf(fabsf(Z), Z_EPS));
            uv[2 * k + 0] = fmaf(X, t, ccx);
            uv[2 * k + 1] = fmaf(Y, t, ccy);
        }

        float2* o = orow + (size_t)v * N;
        if (nvalid == 4) {
            // two back-to-back 16B stores; wave footprint = 2KB contiguous
            float4* o4 = (float4*)o;
            o4[0] = make_float4(uv[0], uv[1], uv[2], uv[3]);
            o4[1] = make_float4(uv[4], uv[5], uv[6], uv[7]);
        } else {
            for (int k = 0; k < nvalid; ++k)
                o[k] = make_float2(uv[2 * k + 0], uv[2 * k + 1]);
        }
    }
}

extern "C" void kernel_launch(void* const* d_in, const int* in_sizes, int n_in,
                              void* d_out, int out_size, void* d_ws, size_t ws_size,
                              hipStream_t stream) {
    const float* points    = (const float*)d_in[0];
    const float* euler     = (const float*)d_in[1];
    const float* txy       = (const float*)d_in[2];
    const float* tdr       = (const float*)d_in[3];
    const float* focal_raw = (const float*)d_in[4];
    const int*   cxp       = (const int*)d_in[5];
    const int*   cyp       = (const int*)d_in[6];

    const int N = in_sizes[0] / 3;
    const int quads = (N + 3) / 4;
    const int blocks = (quads + BLOCK - 1) / BLOCK;

    ba_project_kernel<<<blocks, dim3(BLOCK, 1, 1), 0, stream>>>(
        points, euler, txy, tdr, focal_raw, cxp, cyp, (float2*)d_out, N);
}